// Round 12
// baseline (274.218 us; speedup 1.0000x reference)
//
#include <hip/hip_runtime.h>
#include <math.h>

#define NW   64      // windows (B_)
#define NTOK 256     // tokens per window (N)
#define CDIM 128     // channels (C)
#define NH   4       // heads (H)
#define HD   32      // head dim
#define TKIN 64      // incoming topk
#define TKOUT 32     // outgoing topk
#define KSTR 34      // K LDS row stride (even -> 8B-aligned rows for b64)

typedef float f32x2 __attribute__((ext_vector_type(2)));

static __device__ __forceinline__ float wave_max64f(float x) {
  #pragma unroll
  for (int off = 32; off >= 1; off >>= 1) x = fmaxf(x, __shfl_xor(x, off));
  return x;
}

// Classic Cephes expf exactly as in sse_mathfun / Eigen pexp<float> (SSE2,
// no FMA): every op individually rounded f32. Matches the np reference's
// exp bit patterns (verified round 6). DO NOT TOUCH.
static __device__ __forceinline__ float cephes_expf(float x) {
  x = fminf(x, 88.3762626647949f);
  x = fmaxf(x, -88.3762626647949f);
  float fx = __fadd_rn(__fmul_rn(x, 1.44269504088896341f), 0.5f);
  fx = floorf(fx);
  float tmp = __fmul_rn(fx, 0.693359375f);
  float z2  = __fmul_rn(fx, -2.12194440e-4f);
  x = __fsub_rn(x, tmp);
  x = __fsub_rn(x, z2);
  float z = __fmul_rn(x, x);
  float y = 1.9875691500E-4f;
  y = __fadd_rn(__fmul_rn(y, x), 1.3981999507E-3f);
  y = __fadd_rn(__fmul_rn(y, x), 8.3334519073E-3f);
  y = __fadd_rn(__fmul_rn(y, x), 4.1665795894E-2f);
  y = __fadd_rn(__fmul_rn(y, x), 1.6666665459E-1f);
  y = __fadd_rn(__fmul_rn(y, x), 5.0000001201E-1f);
  y = __fadd_rn(__fmul_rn(y, z), x);
  y = __fadd_rn(y, 1.0f);
  int n = __float2int_rz(fx);              // fx is integral
  float p2n = __int_as_float((n + 127) << 23);
  return __fmul_rn(y, p2n);
}

// numpy pairwise_sum structure for n=64 (unrolled-by-8 C loop); row-uniform
// by commutativity. Verified round 6. DO NOT TOUCH.
static __device__ __forceinline__ float np_pairwise_sum64(float x, int lane) {
  int k = lane & 7;
  float r = __shfl(x, k);
  #pragma unroll
  for (int i2 = 1; i2 < 8; ++i2) r = __fadd_rn(r, __shfl(x, k + 8 * i2));
  float u = __fadd_rn(r, __shfl_xor(r, 1));
  float v = __fadd_rn(u, __shfl_xor(u, 2));
  float w = __fadd_rn(v, __shfl_xor(v, 4));
  return w;
}

// np einsum dot emulation, packed-f32 form: IDENTICAL IEEE ops in IDENTICAL
// order to the verified scalar version (4 accums d-mod-4, separate mul/add,
// (a0+a2)+(a1+a3) finalize). Verified round 10. DO NOT TOUCH.
static __device__ __forceinline__ float np_dot32(const float4* __restrict__ q4,
                                                 const float* __restrict__ krow,
                                                 float scale) {
#pragma clang fp contract(off)
  const f32x2* k2 = (const f32x2*)krow;   // 8B-aligned (KSTR even)
  f32x2 sc; sc.x = scale; sc.y = scale;
  f32x2 A01; A01.x = 0.0f; A01.y = 0.0f;
  f32x2 A23; A23.x = 0.0f; A23.y = 0.0f;
  #pragma unroll
  for (int i4 = 0; i4 < 8; ++i4) {
    float4 q = q4[i4];
    f32x2 q01; q01.x = q.x; q01.y = q.y;
    f32x2 q23; q23.x = q.z; q23.y = q.w;
    A01 = A01 + (q01 * sc) * k2[2 * i4];
    A23 = A23 + (q23 * sc) * k2[2 * i4 + 1];
  }
  f32x2 R = A01 + A23;                    // (acc0+acc2, acc1+acc3)
  return __fadd_rn(R.x, R.y);
}

// Kernel 1: one block per (window, head, QUARTER). 1024 blocks x 512 threads
// (8 waves, 8 rows/wave). Only K is LDS-staged (per-lane random-row gather);
// V rows are wave-uniform -> global reads via L1/L2 (32KB slice per (b,h)).
// LDS 38.9 KB -> 4 blocks/CU; grid 1024 -> 4 blocks/CU realizable -> 32
// waves/CU (2x round 10). Round-11 lesson: no pair-ILP (spills); round-8
// lesson fixed here: grid no longer caps blocks/CU and VGPR budget (64 at
// 8 waves/SIMD) matches the r10-proven register structure.
// Gather chain pipelined 3 rows deep: kidx@r+3, rpi@r+2 (kidx 1 row old),
// bias@r+2 issued post-softmax.
__global__ __launch_bounds__(512, 8) void attn_topk_kernel(
    const float* __restrict__ qkvp,        // [NW, NTOK, 4*CDIM]
    const float* __restrict__ pfa_values,  // [NW, NH, NTOK, TKIN]
    const int*   __restrict__ pfa_indices, // [NW, NH, NTOK, TKIN]
    const int*   __restrict__ rpi,         // [NTOK, NTOK]
    const float* __restrict__ bias_table,  // [961, NH]
    float* __restrict__ xattn,             // [NW*NTOK, CDIM] (pre-projection, = out region)
    float* __restrict__ vals_out,          // [NW, NH, NTOK, TKOUT]
    float* __restrict__ idx_out)           // [NW, NH, NTOK, TKOUT] (as floats)
{
  __shared__ __align__(16) float k_s[NTOK * KSTR];
  __shared__ __align__(16) float a_buf[8 * 64];
  __shared__ __align__(16) float sel_val[8 * 32];
  __shared__ __align__(16) int   sel_idx[8 * 32];

  const int bx = blockIdx.x;               // 0..1023
  const int b  = bx >> 4;
  const int h  = (bx >> 2) & 3;
  const int qq = bx & 3;
  const int tid  = threadIdx.x;
  const int lane = tid & 63;
  const int wid  = tid >> 6;               // 0..7

  const float SCALE_F = 0.17677669529663687f;  // fl32(32^-0.5)
  const float EPS_F   = 1e-10f;

  const float* qbase = qkvp + (size_t)b * (NTOK * 4 * CDIM);
  const float* vglob = qbase + 256 + h * 32;     // part 2, this head

  // Stage K (part 1) for this (b,h): 256 tokens x 32 dims (16 elems/thread).
  #pragma unroll 4
  for (int l = 0; l < 16; ++l) {
    int e   = l * 512 + tid;
    int tok = e >> 5, d = e & 31;
    k_s[tok * KSTR + d] = qbase[tok * 512 + 128 + h * 32 + d];
  }
  __syncthreads();

  const int i0 = qq * 64 + wid * 8;        // this wave's first row
  const size_t rowbase = (size_t)((b * NH + h) * NTOK + i0);
  const int*   idx_p = pfa_indices + rowbase * TKIN + lane;
  const float* val_p = pfa_values  + rowbase * TKIN + lane;

  // Prologue: fill the 3-deep pipeline (rows 0,1,2 kidx/pv; rpi/bias 0,1)
  int   kx0 = idx_p[0],        kx1 = idx_p[TKIN],      kx2 = idx_p[2 * TKIN];
  float pv0 = val_p[0],        pv1 = val_p[TKIN],      pv2 = val_p[2 * TKIN];
  int   rp0 = rpi[(i0 + 0) * NTOK + kx0];
  int   rp1 = rpi[(i0 + 1) * NTOK + kx1];
  float bi0 = bias_table[rp0 * NH + h];
  float bi1 = bias_table[rp1 * NH + h];
  float4 qv[8];
  #pragma unroll
  for (int u = 0; u < 8; ++u)
    qv[u] = ((const float4*)(qbase + i0 * 512 + h * 32))[u];

  for (int r = 0; r < 8; ++r) {
    const int i = i0 + r;
    const size_t rowoff = rowbase + r;
    const int r1 = (r + 1 < 8) ? r + 1 : 7;
    const int r2 = (r + 2 < 8) ? r + 2 : 7;
    const int r3 = (r + 3 < 8) ? r + 3 : 7;

    // ---- pipeline issues: independents + aged-dependency links
    const int   kx3 = idx_p[r3 * TKIN];
    const float pv3 = val_p[r3 * TKIN];
    const int   rp2 = rpi[(i0 + r2) * NTOK + kx2];     // kx2 is 1 row old
    float4 qn[8];
    #pragma unroll
    for (int u = 0; u < 8; ++u)
      qn[u] = ((const float4*)(qbase + (i0 + r1) * 512 + h * 32))[u];
    const float lepe = qbase[i * 512 + 384 + h * 32 + (lane & 31)];

    // QK dot (bit-exact np einsum emulation, packed form)
    const float dot = np_dot32(qv, &k_s[kx0 * KSTR], SCALE_F);
    const float s   = __fadd_rn(dot, bi0);

    // softmax over the 64 keys (one per lane); np-structured sums
    float m  = wave_max64f(s);
    float ex = cephes_expf(__fsub_rn(s, m));
    float sm = np_pairwise_sum64(ex, lane);
    float p0 = __fdiv_rn(ex, sm);
    float a  = __fmul_rn(p0, pv0);             // modulate by prior values
    float s2 = np_pairwise_sum64(a, lane);
    float af = __fdiv_rn(__fadd_rn(a, EPS_F), __fadd_rn(s2, EPS_F));

    // issue bias[r+2] now (rp2 issued earlier; consumed in ~1.5 rows)
    const float bi2 = bias_table[rp2 * NH + h];

    // stable descending rank (ties -> lower slot first); per-wave buffer,
    // in-wave LDS ordering needs no barrier. float4 broadcast reads.
    a_buf[wid * 64 + lane] = af;
    int rank = 0;
    const float4* ab4 = (const float4*)&a_buf[wid * 64];
    #pragma unroll
    for (int j4 = 0; j4 < 16; ++j4) {
      float4 v4 = ab4[j4];
      int j = j4 * 4;
      rank += (v4.x > af || (v4.x == af && (j + 0) < lane)) ? 1 : 0;
      rank += (v4.y > af || (v4.y == af && (j + 1) < lane)) ? 1 : 0;
      rank += (v4.z > af || (v4.z == af && (j + 2) < lane)) ? 1 : 0;
      rank += (v4.w > af || (v4.w == af && (j + 3) < lane)) ? 1 : 0;
    }

    // selection: ranks are a permutation of 0..63 -> push to lane=rank
    float selv = __uint_as_float(
        __builtin_amdgcn_ds_permute(rank << 2, __float_as_uint(af)));
    int   seli = __builtin_amdgcn_ds_permute(rank << 2, kx0);
    if (lane < TKOUT) {
      vals_out[rowoff * TKOUT + lane] = selv;         // coalesced
      idx_out [rowoff * TKOUT + lane] = (float)seli;  // coalesced
      sel_val[wid * 32 + lane] = selv;
      sel_idx[wid * 32 + lane] = seli;
    }

    // AV: lanes (ph,d); sel via b128 broadcasts; V rows wave-uniform from
    // global (L1/L2-resident 32KB slice); fmaf (tolerance region).
    const int ph = lane >> 5, d = lane & 31;
    const float4* sv4 = (const float4*)&sel_val[wid * 32 + ph * 16];
    const int4*   si4 = (const int4*)  &sel_idx[wid * 32 + ph * 16];
    float oacc = 0.0f;
    #pragma unroll
    for (int g = 0; g < 4; ++g) {
      float4 vv = sv4[g];
      int4   ii = si4[g];
      oacc = fmaf(vv.x, vglob[(size_t)ii.x * 512 + d], oacc);
      oacc = fmaf(vv.y, vglob[(size_t)ii.y * 512 + d], oacc);
      oacc = fmaf(vv.z, vglob[(size_t)ii.z * 512 + d], oacc);
      oacc = fmaf(vv.w, vglob[(size_t)ii.w * 512 + d], oacc);
    }
    oacc += __shfl_xor(oacc, 32);
    if (ph == 0) {
      xattn[(size_t)(b * NTOK + i) * CDIM + h * 32 + d] = oacc + lepe;
    }

    // rotate pipeline registers
    kx0 = kx1; kx1 = kx2; kx2 = kx3;
    pv0 = pv1; pv1 = pv2; pv2 = pv3;
    bi0 = bi1; bi1 = bi2;
    #pragma unroll
    for (int u = 0; u < 8; ++u) qv[u] = qn[u];
  }
}

// Kernel 2: in-place projection out = x @ W^T + b over 16 rows per block.
// Each block stages exactly its own 16 rows before overwriting them.
__global__ __launch_bounds__(256) void proj_kernel(
    float* __restrict__ x_out,            // [NW*NTOK, CDIM], read then overwritten
    const float* __restrict__ proj_w,     // [CDIM, CDIM]  (out_c, in_c)
    const float* __restrict__ proj_b)     // [CDIM]
{
  __shared__ __align__(16) float w_t[CDIM * 132];   // w_t[ic][oc], stride 132
  __shared__ __align__(16) float x_s[16 * CDIM];

  const int tid = threadIdx.x;
  const int rowbase = blockIdx.x * 16;

  #pragma unroll 8
  for (int l = 0; l < 64; ++l) {
    int e  = l * 256 + tid;
    int oc = e >> 7, ic = e & 127;
    w_t[ic * 132 + oc] = proj_w[e];
  }
  #pragma unroll
  for (int l = 0; l < 8; ++l) {
    int e = l * 256 + tid;
    x_s[e] = x_out[(size_t)rowbase * CDIM + e];
  }
  __syncthreads();

  const int c0 = tid & 31;   // column group (4 cols)
  const int rs = tid >> 5;   // row slot (rows rs and rs+8)

  float acc0x = 0, acc0y = 0, acc0z = 0, acc0w = 0;
  float acc1x = 0, acc1y = 0, acc1z = 0, acc1w = 0;

  for (int cc4 = 0; cc4 < 32; ++cc4) {
    float4 x0 = *(const float4*)&x_s[rs * CDIM + cc4 * 4];
    float4 x1 = *(const float4*)&x_s[(rs + 8) * CDIM + cc4 * 4];
    const float xs0[4] = {x0.x, x0.y, x0.z, x0.w};
    const float xs1[4] = {x1.x, x1.y, x1.z, x1.w};
    #pragma unroll
    for (int u = 0; u < 4; ++u) {
      int cc = cc4 * 4 + u;
      float4 w4 = *(const float4*)&w_t[cc * 132 + c0 * 4];
      acc0x += xs0[u] * w4.x;  acc0y += xs0[u] * w4.y;
      acc0z += xs0[u] * w4.z;  acc0w += xs0[u] * w4.w;
      acc1x += xs1[u] * w4.x;  acc1y += xs1[u] * w4.y;
      acc1z += xs1[u] * w4.z;  acc1w += xs1[u] * w4.w;
    }
  }

  float4 bb = *(const float4*)&proj_b[c0 * 4];
  float4 o0 = make_float4(acc0x + bb.x, acc0y + bb.y, acc0z + bb.z, acc0w + bb.w);
  float4 o1 = make_float4(acc1x + bb.x, acc1y + bb.y, acc1z + bb.z, acc1w + bb.w);
  *(float4*)&x_out[(size_t)(rowbase + rs) * CDIM + c0 * 4] = o0;
  *(float4*)&x_out[(size_t)(rowbase + rs + 8) * CDIM + c0 * 4] = o1;
}

extern "C" void kernel_launch(void* const* d_in, const int* in_sizes, int n_in,
                              void* d_out, int out_size, void* d_ws, size_t ws_size,
                              hipStream_t stream) {
  (void)in_sizes; (void)n_in; (void)d_ws; (void)ws_size; (void)out_size;

  const float* qkvp        = (const float*)d_in[0];
  const float* pfa_values  = (const float*)d_in[1];
  const int*   pfa_indices = (const int*)  d_in[2];
  const int*   rpi         = (const int*)  d_in[3];
  const float* bias_table  = (const float*)d_in[4];
  const float* proj_w      = (const float*)d_in[5];
  const float* proj_b      = (const float*)d_in[6];

  float* out      = (float*)d_out;                       // [NW*NTOK, CDIM]
  float* vals_out = out + (size_t)NW * NTOK * CDIM;      // [NW,NH,NTOK,TKOUT]
  float* idx_out  = vals_out + (size_t)NW * NH * NTOK * TKOUT;

  // Kernel 1 writes pre-projection xattn into the `out` region (same size),
  // plus vals/new_idx. Kernel 2 projects in place.
  attn_topk_kernel<<<NW * NH * 4, 512, 0, stream>>>(
      qkvp, pfa_values, pfa_indices, rpi, bias_table, out, vals_out, idx_out);
  proj_kernel<<<(NW * NTOK) / 16, 256, 0, stream>>>(out, proj_w, proj_b);
}

// Round 13
// 107.978 us; speedup vs baseline: 2.5396x; 2.5396x over previous
//
#include <hip/hip_runtime.h>
#include <math.h>

#define NW   64      // windows (B_)
#define NTOK 256     // tokens per window (N)
#define CDIM 128     // channels (C)
#define NH   4       // heads (H)
#define HD   32      // head dim
#define TKIN 64      // incoming topk
#define TKOUT 32     // outgoing topk
#define KSTR 34      // K LDS row stride (even -> 8B-aligned rows for b64)

typedef float f32x2 __attribute__((ext_vector_type(2)));

static __device__ __forceinline__ float wave_max64f(float x) {
  #pragma unroll
  for (int off = 32; off >= 1; off >>= 1) x = fmaxf(x, __shfl_xor(x, off));
  return x;
}

// Classic Cephes expf exactly as in sse_mathfun / Eigen pexp<float> (SSE2,
// no FMA): every op individually rounded f32. Matches the np reference's
// exp bit patterns (verified round 6). DO NOT TOUCH.
static __device__ __forceinline__ float cephes_expf(float x) {
  x = fminf(x, 88.3762626647949f);
  x = fmaxf(x, -88.3762626647949f);
  float fx = __fadd_rn(__fmul_rn(x, 1.44269504088896341f), 0.5f);
  fx = floorf(fx);
  float tmp = __fmul_rn(fx, 0.693359375f);
  float z2  = __fmul_rn(fx, -2.12194440e-4f);
  x = __fsub_rn(x, tmp);
  x = __fsub_rn(x, z2);
  float z = __fmul_rn(x, x);
  float y = 1.9875691500E-4f;
  y = __fadd_rn(__fmul_rn(y, x), 1.3981999507E-3f);
  y = __fadd_rn(__fmul_rn(y, x), 8.3334519073E-3f);
  y = __fadd_rn(__fmul_rn(y, x), 4.1665795894E-2f);
  y = __fadd_rn(__fmul_rn(y, x), 1.6666665459E-1f);
  y = __fadd_rn(__fmul_rn(y, x), 5.0000001201E-1f);
  y = __fadd_rn(__fmul_rn(y, z), x);
  y = __fadd_rn(y, 1.0f);
  int n = __float2int_rz(fx);              // fx is integral
  float p2n = __int_as_float((n + 127) << 23);
  return __fmul_rn(y, p2n);
}

// numpy pairwise_sum structure for n=64 (unrolled-by-8 C loop); row-uniform
// by commutativity. Verified round 6. DO NOT TOUCH.
static __device__ __forceinline__ float np_pairwise_sum64(float x, int lane) {
  int k = lane & 7;
  float r = __shfl(x, k);
  #pragma unroll
  for (int i2 = 1; i2 < 8; ++i2) r = __fadd_rn(r, __shfl(x, k + 8 * i2));
  float u = __fadd_rn(r, __shfl_xor(r, 1));
  float v = __fadd_rn(u, __shfl_xor(u, 2));
  float w = __fadd_rn(v, __shfl_xor(v, 4));
  return w;
}

// np einsum dot emulation, packed-f32 form: IDENTICAL IEEE ops in IDENTICAL
// order to the verified scalar version (4 accums d-mod-4, separate mul/add,
// (a0+a2)+(a1+a3) finalize). Verified round 10. DO NOT TOUCH.
static __device__ __forceinline__ float np_dot32(const float4* __restrict__ q4,
                                                 const float* __restrict__ krow,
                                                 float scale) {
#pragma clang fp contract(off)
  const f32x2* k2 = (const f32x2*)krow;   // 8B-aligned (KSTR even)
  f32x2 sc; sc.x = scale; sc.y = scale;
  f32x2 A01; A01.x = 0.0f; A01.y = 0.0f;
  f32x2 A23; A23.x = 0.0f; A23.y = 0.0f;
  #pragma unroll
  for (int i4 = 0; i4 < 8; ++i4) {
    float4 q = q4[i4];
    f32x2 q01; q01.x = q.x; q01.y = q.y;
    f32x2 q23; q23.x = q.z; q23.y = q.w;
    A01 = A01 + (q01 * sc) * k2[2 * i4];
    A23 = A23 + (q23 * sc) * k2[2 * i4 + 1];
  }
  f32x2 R = A01 + A23;                    // (acc0+acc2, acc1+acc3)
  return __fadd_rn(R.x, R.y);
}

// Kernel 1: one block per (window, head, QUARTER). 1024 blocks x 512 threads
// (8 waves, 8 rows/wave). Only K is LDS-staged (per-lane random-row gather);
// V rows are wave-uniform -> global reads via L1/L2 (32KB slice per (b,h)).
// LDS 38.9 KB + VGPR 64 -> 4 blocks/CU x 8 waves = 32 waves/CU; grid 1024
// sustains 4 blocks/CU.
// ROUND-12 LESSON (hard-won): __launch_bounds__ min-waves arg w maps to a
// VGPR cap of ~256/w on this toolchain: w=8 -> 32 VGPR -> total spill
// (WRITE_SIZE 565MB). w=4 -> 64 VGPR, exactly what this register structure
// needs (round 10: VGPR_Count=64, zero spill). NEVER set w>4 here.
// Gather chain pipelined 3 rows deep: kidx@r+3, rpi@r+2 (kidx 1 row old),
// bias@r+2 issued post-softmax.
__global__ __launch_bounds__(512, 4) void attn_topk_kernel(
    const float* __restrict__ qkvp,        // [NW, NTOK, 4*CDIM]
    const float* __restrict__ pfa_values,  // [NW, NH, NTOK, TKIN]
    const int*   __restrict__ pfa_indices, // [NW, NH, NTOK, TKIN]
    const int*   __restrict__ rpi,         // [NTOK, NTOK]
    const float* __restrict__ bias_table,  // [961, NH]
    float* __restrict__ xattn,             // [NW*NTOK, CDIM] (pre-projection, = out region)
    float* __restrict__ vals_out,          // [NW, NH, NTOK, TKOUT]
    float* __restrict__ idx_out)           // [NW, NH, NTOK, TKOUT] (as floats)
{
  __shared__ __align__(16) float k_s[NTOK * KSTR];
  __shared__ __align__(16) float a_buf[8 * 64];
  __shared__ __align__(16) float sel_val[8 * 32];
  __shared__ __align__(16) int   sel_idx[8 * 32];

  const int bx = blockIdx.x;               // 0..1023
  const int b  = bx >> 4;
  const int h  = (bx >> 2) & 3;
  const int qq = bx & 3;
  const int tid  = threadIdx.x;
  const int lane = tid & 63;
  const int wid  = tid >> 6;               // 0..7

  const float SCALE_F = 0.17677669529663687f;  // fl32(32^-0.5)
  const float EPS_F   = 1e-10f;

  const float* qbase = qkvp + (size_t)b * (NTOK * 4 * CDIM);
  const float* vglob = qbase + 256 + h * 32;     // part 2, this head

  // Stage K (part 1) for this (b,h): 256 tokens x 32 dims (16 elems/thread).
  #pragma unroll 4
  for (int l = 0; l < 16; ++l) {
    int e   = l * 512 + tid;
    int tok = e >> 5, d = e & 31;
    k_s[tok * KSTR + d] = qbase[tok * 512 + 128 + h * 32 + d];
  }
  __syncthreads();

  const int i0 = qq * 64 + wid * 8;        // this wave's first row
  const size_t rowbase = (size_t)((b * NH + h) * NTOK + i0);
  const int*   idx_p = pfa_indices + rowbase * TKIN + lane;
  const float* val_p = pfa_values  + rowbase * TKIN + lane;

  // Prologue: fill the 3-deep pipeline (rows 0,1,2 kidx/pv; rpi/bias 0,1)
  int   kx0 = idx_p[0],        kx1 = idx_p[TKIN],      kx2 = idx_p[2 * TKIN];
  float pv0 = val_p[0],        pv1 = val_p[TKIN],      pv2 = val_p[2 * TKIN];
  int   rp0 = rpi[(i0 + 0) * NTOK + kx0];
  int   rp1 = rpi[(i0 + 1) * NTOK + kx1];
  float bi0 = bias_table[rp0 * NH + h];
  float bi1 = bias_table[rp1 * NH + h];
  float4 qv[8];
  #pragma unroll
  for (int u = 0; u < 8; ++u)
    qv[u] = ((const float4*)(qbase + i0 * 512 + h * 32))[u];

  for (int r = 0; r < 8; ++r) {
    const int i = i0 + r;
    const size_t rowoff = rowbase + r;
    const int r1 = (r + 1 < 8) ? r + 1 : 7;
    const int r2 = (r + 2 < 8) ? r + 2 : 7;
    const int r3 = (r + 3 < 8) ? r + 3 : 7;

    // ---- pipeline issues: independents + aged-dependency links
    const int   kx3 = idx_p[r3 * TKIN];
    const float pv3 = val_p[r3 * TKIN];
    const int   rp2 = rpi[(i0 + r2) * NTOK + kx2];     // kx2 is 1 row old
    float4 qn[8];
    #pragma unroll
    for (int u = 0; u < 8; ++u)
      qn[u] = ((const float4*)(qbase + (i0 + r1) * 512 + h * 32))[u];
    const float lepe = qbase[i * 512 + 384 + h * 32 + (lane & 31)];

    // QK dot (bit-exact np einsum emulation, packed form)
    const float dot = np_dot32(qv, &k_s[kx0 * KSTR], SCALE_F);
    const float s   = __fadd_rn(dot, bi0);

    // softmax over the 64 keys (one per lane); np-structured sums
    float m  = wave_max64f(s);
    float ex = cephes_expf(__fsub_rn(s, m));
    float sm = np_pairwise_sum64(ex, lane);
    float p0 = __fdiv_rn(ex, sm);
    float a  = __fmul_rn(p0, pv0);             // modulate by prior values
    float s2 = np_pairwise_sum64(a, lane);
    float af = __fdiv_rn(__fadd_rn(a, EPS_F), __fadd_rn(s2, EPS_F));

    // issue bias[r+2] now (rp2 issued earlier; consumed in ~1.5 rows)
    const float bi2 = bias_table[rp2 * NH + h];

    // stable descending rank (ties -> lower slot first); per-wave buffer,
    // in-wave LDS ordering needs no barrier. float4 broadcast reads.
    a_buf[wid * 64 + lane] = af;
    int rank = 0;
    const float4* ab4 = (const float4*)&a_buf[wid * 64];
    #pragma unroll
    for (int j4 = 0; j4 < 16; ++j4) {
      float4 v4 = ab4[j4];
      int j = j4 * 4;
      rank += (v4.x > af || (v4.x == af && (j + 0) < lane)) ? 1 : 0;
      rank += (v4.y > af || (v4.y == af && (j + 1) < lane)) ? 1 : 0;
      rank += (v4.z > af || (v4.z == af && (j + 2) < lane)) ? 1 : 0;
      rank += (v4.w > af || (v4.w == af && (j + 3) < lane)) ? 1 : 0;
    }

    // selection: ranks are a permutation of 0..63 -> push to lane=rank
    float selv = __uint_as_float(
        __builtin_amdgcn_ds_permute(rank << 2, __float_as_uint(af)));
    int   seli = __builtin_amdgcn_ds_permute(rank << 2, kx0);
    if (lane < TKOUT) {
      vals_out[rowoff * TKOUT + lane] = selv;         // coalesced
      idx_out [rowoff * TKOUT + lane] = (float)seli;  // coalesced
      sel_val[wid * 32 + lane] = selv;
      sel_idx[wid * 32 + lane] = seli;
    }

    // AV: lanes (ph,d); sel via b128 broadcasts; V rows wave-uniform from
    // global (L1/L2-resident 32KB slice); fmaf (tolerance region).
    const int ph = lane >> 5, d = lane & 31;
    const float4* sv4 = (const float4*)&sel_val[wid * 32 + ph * 16];
    const int4*   si4 = (const int4*)  &sel_idx[wid * 32 + ph * 16];
    float oacc = 0.0f;
    #pragma unroll
    for (int g = 0; g < 4; ++g) {
      float4 vv = sv4[g];
      int4   ii = si4[g];
      oacc = fmaf(vv.x, vglob[(size_t)ii.x * 512 + d], oacc);
      oacc = fmaf(vv.y, vglob[(size_t)ii.y * 512 + d], oacc);
      oacc = fmaf(vv.z, vglob[(size_t)ii.z * 512 + d], oacc);
      oacc = fmaf(vv.w, vglob[(size_t)ii.w * 512 + d], oacc);
    }
    oacc += __shfl_xor(oacc, 32);
    if (ph == 0) {
      xattn[(size_t)(b * NTOK + i) * CDIM + h * 32 + d] = oacc + lepe;
    }

    // rotate pipeline registers
    kx0 = kx1; kx1 = kx2; kx2 = kx3;
    pv0 = pv1; pv1 = pv2; pv2 = pv3;
    bi0 = bi1; bi1 = bi2;
    #pragma unroll
    for (int u = 0; u < 8; ++u) qv[u] = qn[u];
  }
}

// Kernel 2: in-place projection out = x @ W^T + b over 16 rows per block.
// Each block stages exactly its own 16 rows before overwriting them.
__global__ __launch_bounds__(256) void proj_kernel(
    float* __restrict__ x_out,            // [NW*NTOK, CDIM], read then overwritten
    const float* __restrict__ proj_w,     // [CDIM, CDIM]  (out_c, in_c)
    const float* __restrict__ proj_b)     // [CDIM]
{
  __shared__ __align__(16) float w_t[CDIM * 132];   // w_t[ic][oc], stride 132
  __shared__ __align__(16) float x_s[16 * CDIM];

  const int tid = threadIdx.x;
  const int rowbase = blockIdx.x * 16;

  #pragma unroll 8
  for (int l = 0; l < 64; ++l) {
    int e  = l * 256 + tid;
    int oc = e >> 7, ic = e & 127;
    w_t[ic * 132 + oc] = proj_w[e];
  }
  #pragma unroll
  for (int l = 0; l < 8; ++l) {
    int e = l * 256 + tid;
    x_s[e] = x_out[(size_t)rowbase * CDIM + e];
  }
  __syncthreads();

  const int c0 = tid & 31;   // column group (4 cols)
  const int rs = tid >> 5;   // row slot (rows rs and rs+8)

  float acc0x = 0, acc0y = 0, acc0z = 0, acc0w = 0;
  float acc1x = 0, acc1y = 0, acc1z = 0, acc1w = 0;

  for (int cc4 = 0; cc4 < 32; ++cc4) {
    float4 x0 = *(const float4*)&x_s[rs * CDIM + cc4 * 4];
    float4 x1 = *(const float4*)&x_s[(rs + 8) * CDIM + cc4 * 4];
    const float xs0[4] = {x0.x, x0.y, x0.z, x0.w};
    const float xs1[4] = {x1.x, x1.y, x1.z, x1.w};
    #pragma unroll
    for (int u = 0; u < 4; ++u) {
      int cc = cc4 * 4 + u;
      float4 w4 = *(const float4*)&w_t[cc * 132 + c0 * 4];
      acc0x += xs0[u] * w4.x;  acc0y += xs0[u] * w4.y;
      acc0z += xs0[u] * w4.z;  acc0w += xs0[u] * w4.w;
      acc1x += xs1[u] * w4.x;  acc1y += xs1[u] * w4.y;
      acc1z += xs1[u] * w4.z;  acc1w += xs1[u] * w4.w;
    }
  }

  float4 bb = *(const float4*)&proj_b[c0 * 4];
  float4 o0 = make_float4(acc0x + bb.x, acc0y + bb.y, acc0z + bb.z, acc0w + bb.w);
  float4 o1 = make_float4(acc1x + bb.x, acc1y + bb.y, acc1z + bb.z, acc1w + bb.w);
  *(float4*)&x_out[(size_t)(rowbase + rs) * CDIM + c0 * 4] = o0;
  *(float4*)&x_out[(size_t)(rowbase + rs + 8) * CDIM + c0 * 4] = o1;
}

extern "C" void kernel_launch(void* const* d_in, const int* in_sizes, int n_in,
                              void* d_out, int out_size, void* d_ws, size_t ws_size,
                              hipStream_t stream) {
  (void)in_sizes; (void)n_in; (void)d_ws; (void)ws_size; (void)out_size;

  const float* qkvp        = (const float*)d_in[0];
  const float* pfa_values  = (const float*)d_in[1];
  const int*   pfa_indices = (const int*)  d_in[2];
  const int*   rpi         = (const int*)  d_in[3];
  const float* bias_table  = (const float*)d_in[4];
  const float* proj_w      = (const float*)d_in[5];
  const float* proj_b      = (const float*)d_in[6];

  float* out      = (float*)d_out;                       // [NW*NTOK, CDIM]
  float* vals_out = out + (size_t)NW * NTOK * CDIM;      // [NW,NH,NTOK,TKOUT]
  float* idx_out  = vals_out + (size_t)NW * NH * NTOK * TKOUT;

  // Kernel 1 writes pre-projection xattn into the `out` region (same size),
  // plus vals/new_idx. Kernel 2 projects in place.
  attn_topk_kernel<<<NW * NH * 4, 512, 0, stream>>>(
      qkvp, pfa_values, pfa_indices, rpi, bias_table, out, vals_out, idx_out);
  proj_kernel<<<(NW * NTOK) / 16, 256, 0, stream>>>(out, proj_w, proj_b);
}

// Round 14
// 81.678 us; speedup vs baseline: 3.3573x; 1.3220x over previous
//
#include <hip/hip_runtime.h>
#include <math.h>

#define NW   64      // windows (B_)
#define NTOK 256     // tokens per window (N)
#define CDIM 128     // channels (C)
#define NH   4       // heads (H)
#define HD   32      // head dim
#define TKIN 64      // incoming topk
#define TKOUT 32     // outgoing topk
#define KSTR 36      // K/V LDS row stride (multiple of 4 -> 16B-aligned rows)

typedef float f32x2 __attribute__((ext_vector_type(2)));

// DPP lane move (VALU pipe, ~2-4 cyc vs ~40 for ds_bpermute).
// ctrl: 0x00-0xFF quad_perm; 0x121-0x12F row_ror:1..15 (within 16-lane rows).
template <int CTRL>
static __device__ __forceinline__ float dpp_mov_f(float x) {
  return __int_as_float(__builtin_amdgcn_update_dpp(
      0, __float_as_int(x), CTRL, 0xF, 0xF, true));
}

// Exact full-wave max (fmaxf is exactly commutative/associative on finite
// data, so ANY covering reduction structure gives bit-identical results):
// ^1,^2 via quad_perm; rotate-reduce ror4+ror8 covers the 16-lane row;
// ^16 via ds_swizzle; ^32 via bpermute. DS ops: 6 -> 2.
static __device__ __forceinline__ float wave_max64f(float x) {
  x = fmaxf(x, dpp_mov_f<0xB1>(x));    // quad_perm [1,0,3,2] == lane^1
  x = fmaxf(x, dpp_mov_f<0x4E>(x));    // quad_perm [2,3,0,1] == lane^2
  x = fmaxf(x, dpp_mov_f<0x124>(x));   // row_ror:4 (covers neighbor quad)
  x = fmaxf(x, dpp_mov_f<0x128>(x));   // row_ror:8 == lane^8 within row
  x = fmaxf(x, __int_as_float(
      __builtin_amdgcn_ds_swizzle(__float_as_int(x), 0x401F)));  // lane^16
  x = fmaxf(x, __shfl_xor(x, 32));                               // lane^32
  return x;
}

// Classic Cephes expf exactly as in sse_mathfun / Eigen pexp<float> (SSE2,
// no FMA): every op individually rounded f32. Matches the np reference's
// exp bit patterns (verified round 6). DO NOT TOUCH.
static __device__ __forceinline__ float cephes_expf(float x) {
  x = fminf(x, 88.3762626647949f);
  x = fmaxf(x, -88.3762626647949f);
  float fx = __fadd_rn(__fmul_rn(x, 1.44269504088896341f), 0.5f);
  fx = floorf(fx);
  float tmp = __fmul_rn(fx, 0.693359375f);
  float z2  = __fmul_rn(fx, -2.12194440e-4f);
  x = __fsub_rn(x, tmp);
  x = __fsub_rn(x, z2);
  float z = __fmul_rn(x, x);
  float y = 1.9875691500E-4f;
  y = __fadd_rn(__fmul_rn(y, x), 1.3981999507E-3f);
  y = __fadd_rn(__fmul_rn(y, x), 8.3334519073E-3f);
  y = __fadd_rn(__fmul_rn(y, x), 4.1665795894E-2f);
  y = __fadd_rn(__fmul_rn(y, x), 1.6666665459E-1f);
  y = __fadd_rn(__fmul_rn(y, x), 5.0000001201E-1f);
  y = __fadd_rn(__fmul_rn(y, z), x);
  y = __fadd_rn(y, 1.0f);
  int n = __float2int_rz(fx);              // fx is integral
  float p2n = __int_as_float((n + 127) << 23);
  return __fmul_rn(y, p2n);
}

// numpy pairwise_sum for n=64 (unrolled-by-8 C loop), bit-exact:
//   r[k] = strict left fold x[k]+x[k+8]+...+x[k+56]    (8 bpermutes, kept)
//   res  = ((r0+r1)+(r2+r3)) + ((r4+r5)+(r6+r7))
// Stage 2 via DPP: ^1 and ^2 are exact quad_perms. For the ^4 step, v[l]
// depends ONLY on bit2 of l (v[l] = (r[a]+r[a^1])+(r[a^2]+r[a^3]), a=l&4),
// so row_ror:4 delivers exactly v[l^4]; lanes with bit2=1 compute high+low
// instead of low+high -> identical by commutativity -> uniform, bit-exact.
static __device__ __forceinline__ float np_pairwise_sum64(float x, int lane) {
  int k = lane & 7;
  float r = __shfl(x, k);
  #pragma unroll
  for (int i2 = 1; i2 < 8; ++i2) r = __fadd_rn(r, __shfl(x, k + 8 * i2));
  float u = __fadd_rn(r, dpp_mov_f<0xB1>(r));    // + r[l^1]
  float v = __fadd_rn(u, dpp_mov_f<0x4E>(u));    // + u[l^2]
  float w = __fadd_rn(v, dpp_mov_f<0x124>(v));   // + v[l^4] (see proof above)
  return w;
}

// np einsum dot emulation, packed-f32 form: IDENTICAL IEEE ops in IDENTICAL
// order to the verified scalar version (4 accums d-mod-4, separate mul/add,
// (a0+a2)+(a1+a3) finalize). K rows 16B-aligned (KSTR=36) -> 8x ds_read_b128
// instead of 16x b64. Verified round 10 (op order unchanged). DO NOT TOUCH.
static __device__ __forceinline__ float np_dot32(const float4* __restrict__ q4,
                                                 const float* __restrict__ krow,
                                                 float scale) {
#pragma clang fp contract(off)
  const float4* k4p = (const float4*)krow;  // 16B-aligned
  f32x2 sc; sc.x = scale; sc.y = scale;
  f32x2 A01; A01.x = 0.0f; A01.y = 0.0f;
  f32x2 A23; A23.x = 0.0f; A23.y = 0.0f;
  #pragma unroll
  for (int i4 = 0; i4 < 8; ++i4) {
    float4 q = q4[i4];
    float4 kk = k4p[i4];
    f32x2 q01; q01.x = q.x; q01.y = q.y;
    f32x2 q23; q23.x = q.z; q23.y = q.w;
    f32x2 k01; k01.x = kk.x; k01.y = kk.y;
    f32x2 k23; k23.x = kk.z; k23.y = kk.w;
    A01 = A01 + (q01 * sc) * k01;
    A23 = A23 + (q23 * sc) * k23;
  }
  f32x2 R = A01 + A23;                    // (acc0+acc2, acc1+acc3)
  return __fadd_rn(R.x, R.y);
}

// Kernel 1: one block per (window, head, half) — the round-10 structure
// (best measured: 89.6us attn), with cross-lane traffic moved DS->DPP and
// the K-gather widened to b128. 512 threads = 8 waves; each wave owns 16
// rows, no per-row block barriers. K and V in LDS (stride 36).
// Gather chain pipelined 3 rows deep: kidx@r+3, rpi@r+2 (kidx 1 row old),
// bias@r+2 issued post-softmax.
// LESSONS: launch_bounds min-waves w caps VGPR at ~256/w: w=4 -> 64 (fits,
// r10-proven); w=8 -> 32 -> total spill (r12). Occupancy is pinned ~16
// waves/CU (r13: cutting LDS to 38.9KB did NOT raise it) — optimize
// per-wave latency, not occupancy.
__global__ __launch_bounds__(512, 4) void attn_topk_kernel(
    const float* __restrict__ qkvp,        // [NW, NTOK, 4*CDIM]
    const float* __restrict__ pfa_values,  // [NW, NH, NTOK, TKIN]
    const int*   __restrict__ pfa_indices, // [NW, NH, NTOK, TKIN]
    const int*   __restrict__ rpi,         // [NTOK, NTOK]
    const float* __restrict__ bias_table,  // [961, NH]
    float* __restrict__ xattn,             // [NW*NTOK, CDIM] (pre-projection, = out region)
    float* __restrict__ vals_out,          // [NW, NH, NTOK, TKOUT]
    float* __restrict__ idx_out)           // [NW, NH, NTOK, TKOUT] (as floats)
{
  __shared__ __align__(16) float k_s[NTOK * KSTR];   // 36,864 B
  __shared__ __align__(16) float v_s[NTOK * KSTR];   // 36,864 B
  __shared__ __align__(16) unsigned long long key_buf[8 * 64];  // 4,096 B
  __shared__ __align__(16) float sel_val[8 * 32];    // 1,024 B
  __shared__ __align__(16) int   sel_idx[8 * 32];    // 1,024 B -> 79,872 total

  const int bx    = blockIdx.x;            // 0..511
  const int b     = bx >> 3;
  const int h     = (bx >> 1) & 3;
  const int qhalf = bx & 1;
  const int tid   = threadIdx.x;
  const int lane  = tid & 63;
  const int wid   = tid >> 6;              // 0..7

  const float SCALE_F = 0.17677669529663687f;  // fl32(32^-0.5)
  const float EPS_F   = 1e-10f;

  const float* qbase = qkvp + (size_t)b * (NTOK * 4 * CDIM);

  // Stage K (part 1) and V (part 2) for this (b,h): 256 tokens x 32 dims.
  #pragma unroll 4
  for (int l = 0; l < 16; ++l) {
    int e   = l * 512 + tid;
    int tok = e >> 5, d = e & 31;
    int g   = tok * 512 + h * 32 + d;
    k_s[tok * KSTR + d] = qbase[g + 128];
    v_s[tok * KSTR + d] = qbase[g + 256];
  }
  __syncthreads();

  const int i0 = qhalf * 128 + wid * 16;   // this wave's first row
  const size_t rowbase = (size_t)((b * NH + h) * NTOK + i0);
  const int*   idx_p = pfa_indices + rowbase * TKIN + lane;
  const float* val_p = pfa_values  + rowbase * TKIN + lane;

  // Prologue: fill the 3-deep pipeline (rows 0,1,2 kidx/pv; rpi/bias 0,1)
  int   kx0 = idx_p[0],        kx1 = idx_p[TKIN],      kx2 = idx_p[2 * TKIN];
  float pv0 = val_p[0],        pv1 = val_p[TKIN],      pv2 = val_p[2 * TKIN];
  int   rp0 = rpi[(i0 + 0) * NTOK + kx0];
  int   rp1 = rpi[(i0 + 1) * NTOK + kx1];
  float bi0 = bias_table[rp0 * NH + h];
  float bi1 = bias_table[rp1 * NH + h];
  float4 qv[8];
  #pragma unroll
  for (int u = 0; u < 8; ++u)
    qv[u] = ((const float4*)(qbase + i0 * 512 + h * 32))[u];

  for (int r = 0; r < 16; ++r) {
    const int i = i0 + r;
    const size_t rowoff = rowbase + r;
    const int r1 = (r + 1 < 16) ? r + 1 : 15;
    const int r2 = (r + 2 < 16) ? r + 2 : 15;
    const int r3 = (r + 3 < 16) ? r + 3 : 15;

    // ---- pipeline issues: independents + aged-dependency links
    const int   kx3 = idx_p[r3 * TKIN];
    const float pv3 = val_p[r3 * TKIN];
    const int   rp2 = rpi[(i0 + r2) * NTOK + kx2];     // kx2 is 1 row old
    float4 qn[8];
    #pragma unroll
    for (int u = 0; u < 8; ++u)
      qn[u] = ((const float4*)(qbase + (i0 + r1) * 512 + h * 32))[u];
    const float lepe = qbase[i * 512 + 384 + h * 32 + (lane & 31)];

    // QK dot (bit-exact np einsum emulation, packed + b128 K reads)
    const float dot = np_dot32(qv, &k_s[kx0 * KSTR], SCALE_F);
    const float s   = __fadd_rn(dot, bi0);

    // softmax over the 64 keys (one per lane); np-structured sums
    float m  = wave_max64f(s);
    float ex = cephes_expf(__fsub_rn(s, m));
    float sm = np_pairwise_sum64(ex, lane);
    float p0 = __fdiv_rn(ex, sm);
    float a  = __fmul_rn(p0, pv0);             // modulate by prior values
    float s2 = np_pairwise_sum64(a, lane);
    float af = __fdiv_rn(__fadd_rn(a, EPS_F), __fadd_rn(s2, EPS_F));

    // issue bias[r+2] now (rp2 issued ~500cyc ago; consumed in ~1.5 rows)
    const float bi2 = bias_table[rp2 * NH + h];

    // stable descending rank via u64 keys: (af_bits<<32)|(63-lane).
    // pack_j > pack_me with equal af  <=>  j < me  (ties -> lower slot).
    const unsigned long long kme =
        ((unsigned long long)__float_as_uint(af) << 32) | (unsigned)(63 - lane);
    key_buf[wid * 64 + lane] = kme;
    int rank = 0;
    const ulonglong2* kb2 = (const ulonglong2*)&key_buf[wid * 64];
    #pragma unroll
    for (int j2 = 0; j2 < 32; ++j2) {
      ulonglong2 kk = kb2[j2];
      rank += (kk.x > kme) ? 1 : 0;
      rank += (kk.y > kme) ? 1 : 0;
    }

    // selection: ranks are a permutation of 0..63 -> push to lane=rank
    float selv = __uint_as_float(
        __builtin_amdgcn_ds_permute(rank << 2, __float_as_uint(af)));
    int   seli = __builtin_amdgcn_ds_permute(rank << 2, kx0);
    if (lane < TKOUT) {
      vals_out[rowoff * TKOUT + lane] = selv;         // coalesced
      idx_out [rowoff * TKOUT + lane] = (float)seli;  // coalesced
      sel_val[wid * 32 + lane] = selv;
      sel_idx[wid * 32 + lane] = seli;
    }

    // AV: lanes (ph,d); sel via b128 broadcasts; fmaf (tolerance region)
    const int ph = lane >> 5, d = lane & 31;
    const float4* sv4 = (const float4*)&sel_val[wid * 32 + ph * 16];
    const int4*   si4 = (const int4*)  &sel_idx[wid * 32 + ph * 16];
    float oacc = 0.0f;
    #pragma unroll
    for (int g = 0; g < 4; ++g) {
      float4 vv = sv4[g];
      int4   ii = si4[g];
      oacc = fmaf(vv.x, v_s[ii.x * KSTR + d], oacc);
      oacc = fmaf(vv.y, v_s[ii.y * KSTR + d], oacc);
      oacc = fmaf(vv.z, v_s[ii.z * KSTR + d], oacc);
      oacc = fmaf(vv.w, v_s[ii.w * KSTR + d], oacc);
    }
    oacc += __shfl_xor(oacc, 32);
    if (ph == 0) {
      xattn[(size_t)(b * NTOK + i) * CDIM + h * 32 + d] = oacc + lepe;
    }

    // rotate pipeline registers
    kx0 = kx1; kx1 = kx2; kx2 = kx3;
    pv0 = pv1; pv1 = pv2; pv2 = pv3;
    bi0 = bi1; bi1 = bi2;
    #pragma unroll
    for (int u = 0; u < 8; ++u) qv[u] = qn[u];
  }
}

// Kernel 2: in-place projection out = x @ W^T + b over 16 rows per block.
// Each block stages exactly its own 16 rows before overwriting them.
__global__ __launch_bounds__(256) void proj_kernel(
    float* __restrict__ x_out,            // [NW*NTOK, CDIM], read then overwritten
    const float* __restrict__ proj_w,     // [CDIM, CDIM]  (out_c, in_c)
    const float* __restrict__ proj_b)     // [CDIM]
{
  __shared__ __align__(16) float w_t[CDIM * 132];   // w_t[ic][oc], stride 132
  __shared__ __align__(16) float x_s[16 * CDIM];

  const int tid = threadIdx.x;
  const int rowbase = blockIdx.x * 16;

  #pragma unroll 8
  for (int l = 0; l < 64; ++l) {
    int e  = l * 256 + tid;
    int oc = e >> 7, ic = e & 127;
    w_t[ic * 132 + oc] = proj_w[e];
  }
  #pragma unroll
  for (int l = 0; l < 8; ++l) {
    int e = l * 256 + tid;
    x_s[e] = x_out[(size_t)rowbase * CDIM + e];
  }
  __syncthreads();

  const int c0 = tid & 31;   // column group (4 cols)
  const int rs = tid >> 5;   // row slot (rows rs and rs+8)

  float acc0x = 0, acc0y = 0, acc0z = 0, acc0w = 0;
  float acc1x = 0, acc1y = 0, acc1z = 0, acc1w = 0;

  for (int cc4 = 0; cc4 < 32; ++cc4) {
    float4 x0 = *(const float4*)&x_s[rs * CDIM + cc4 * 4];
    float4 x1 = *(const float4*)&x_s[(rs + 8) * CDIM + cc4 * 4];
    const float xs0[4] = {x0.x, x0.y, x0.z, x0.w};
    const float xs1[4] = {x1.x, x1.y, x1.z, x1.w};
    #pragma unroll
    for (int u = 0; u < 4; ++u) {
      int cc = cc4 * 4 + u;
      float4 w4 = *(const float4*)&w_t[cc * 132 + c0 * 4];
      acc0x += xs0[u] * w4.x;  acc0y += xs0[u] * w4.y;
      acc0z += xs0[u] * w4.z;  acc0w += xs0[u] * w4.w;
      acc1x += xs1[u] * w4.x;  acc1y += xs1[u] * w4.y;
      acc1z += xs1[u] * w4.z;  acc1w += xs1[u] * w4.w;
    }
  }

  float4 bb = *(const float4*)&proj_b[c0 * 4];
  float4 o0 = make_float4(acc0x + bb.x, acc0y + bb.y, acc0z + bb.z, acc0w + bb.w);
  float4 o1 = make_float4(acc1x + bb.x, acc1y + bb.y, acc1z + bb.z, acc1w + bb.w);
  *(float4*)&x_out[(size_t)(rowbase + rs) * CDIM + c0 * 4] = o0;
  *(float4*)&x_out[(size_t)(rowbase + rs + 8) * CDIM + c0 * 4] = o1;
}

extern "C" void kernel_launch(void* const* d_in, const int* in_sizes, int n_in,
                              void* d_out, int out_size, void* d_ws, size_t ws_size,
                              hipStream_t stream) {
  (void)in_sizes; (void)n_in; (void)d_ws; (void)ws_size; (void)out_size;

  const float* qkvp        = (const float*)d_in[0];
  const float* pfa_values  = (const float*)d_in[1];
  const int*   pfa_indices = (const int*)  d_in[2];
  const int*   rpi         = (const int*)  d_in[3];
  const float* bias_table  = (const float*)d_in[4];
  const float* proj_w      = (const float*)d_in[5];
  const float* proj_b      = (const float*)d_in[6];

  float* out      = (float*)d_out;                       // [NW*NTOK, CDIM]
  float* vals_out = out + (size_t)NW * NTOK * CDIM;      // [NW,NH,NTOK,TKOUT]
  float* idx_out  = vals_out + (size_t)NW * NH * NTOK * TKOUT;

  // Kernel 1 writes pre-projection xattn into the `out` region (same size),
  // plus vals/new_idx. Kernel 2 projects in place.
  attn_topk_kernel<<<NW * NH * 2, 512, 0, stream>>>(
      qkvp, pfa_values, pfa_indices, rpi, bias_table, out, vals_out, idx_out);
  proj_kernel<<<(NW * NTOK) / 16, 256, 0, stream>>>(out, proj_w, proj_b);
}